// Round 11
// baseline (1860.013 us; speedup 1.0000x reference)
//
#include <hip/hip_runtime.h>

// ---------------------------------------------------------------------------
// CMAPFeatureExtractor: twin-branch GCN autoencoder on MI355X (gfx950).
// Round 11: mix3 fused into GEMM A-staging (gemm128m): reg-stage A' =
// sum_j adj[b,i,j]*x[b,j,:] with ds_write to swizzled LDS; B stays
// global_load_lds. Kills 6 mix3 dispatches (~2.3 GB HBM traffic).
// Plain gemm256 (round-7) kept for g-proj; gemm128 (round-8) for c-proj/te.
// ---------------------------------------------------------------------------

typedef __attribute__((ext_vector_type(8))) short s16x8;   // 8 x bf16
typedef __attribute__((ext_vector_type(4))) short s16x4;   // 4 x bf16
typedef __attribute__((ext_vector_type(4))) float f32x4;

#define DEV static __device__ __forceinline__

DEV float b2f(ushort u) { return __builtin_bit_cast(float, (unsigned)u << 16); }
DEV ushort f2b(float f) {
  unsigned x = __builtin_bit_cast(unsigned, f);
  unsigned r = x + 0x7fffu + ((x >> 16) & 1u);   // RNE; inputs are finite
  return (ushort)(r >> 16);
}

typedef const __attribute__((address_space(1))) void* gas_ptr;
typedef __attribute__((address_space(3))) void* las_ptr;

// ---------------------------------------------------------------------------
// 256^2 GEMM, 4-phase fragment-reuse schedule (round-7, verified).
// M%256==0, N%256==0, K%128==0. 8 waves, wave-tile 128x64.
// ---------------------------------------------------------------------------
template<int ACT>   // 0 = relu, 1 = silu
__global__ __launch_bounds__(512, 2) void gemm256(
    const ushort* __restrict__ A, const ushort* __restrict__ BT,
    const float* __restrict__ bias, ushort* __restrict__ C,
    int M, int N, int K)
{
  __shared__ __align__(16) ushort ldsbuf[65536];   // 128 KiB
  char* Lb = (char*)ldsbuf;

  const int tid = threadIdx.x, lane = tid & 63, w = tid >> 6;
  const int wm = w >> 2, wn = w & 3;

  const int gx  = gridDim.x;
  const int nwg = gx * gridDim.y;
  const int wid = blockIdx.y * gx + blockIdx.x;
  const int q   = nwg >> 3;
  const int Lw  = (wid & 7) * q + (wid >> 3);
  const int bn  = Lw % gx;
  const int bm  = Lw / gx;

  const ushort* Abase = A  + (size_t)bm * 256 * K;
  const ushort* Bbase = BT + (size_t)bn * 256 * K;
  const int T = K >> 6;

  const int srow = w * 8 + (lane >> 3);
  const int scol = (((lane & 7) ^ (lane >> 3)) << 3);

#define STAGE(buf, m, half, Gb, k0)                                          \
  {                                                                          \
    _Pragma("unroll") for (int _j = 0; _j < 2; ++_j) {                       \
      const ushort* _src = (Gb) + (size_t)((half)*128 + _j*64 + srow) * K    \
                           + (k0) + scol;                                    \
      ushort* _dst = (ushort*)(Lb + ((buf)*2 + (m)) * 32768                  \
                               + ((half)*128 + _j*64 + w*8) * 128);          \
      __builtin_amdgcn_global_load_lds((gas_ptr)_src, (las_ptr)_dst, 16,0,0);\
    }                                                                        \
  }

  const int lr = lane & 15, lk = lane >> 4;

#define READ_A(dst, c, mh)                                                   \
  _Pragma("unroll") for (int _i = 0; _i < 4; ++_i)                           \
    _Pragma("unroll") for (int _kk = 0; _kk < 2; ++_kk) {                    \
      const int _r   = (mh)*128 + wm*64 + _i*16 + lr;                        \
      const int _cbb = _kk*64 + lk*16;                                       \
      dst[_i][_kk] = *(const s16x8*)(Lb + ((c)*2 + 0)*32768 + _r*128         \
                                     + (_cbb ^ ((_r & 7) << 4)));            \
    }
#define READ_B(dst, c, nh)                                                   \
  _Pragma("unroll") for (int _p = 0; _p < 2; ++_p)                           \
    _Pragma("unroll") for (int _kk = 0; _kk < 2; ++_kk) {                    \
      const int _r   = (nh)*128 + wn*32 + _p*16 + lr;                        \
      const int _cbb = _kk*64 + lk*16;                                       \
      dst[_p][_kk] = *(const s16x8*)(Lb + ((c)*2 + 1)*32768 + _r*128         \
                                     + (_cbb ^ ((_r & 7) << 4)));            \
    }

#define MFMA_Q(mh, nh)                                                       \
  _Pragma("unroll") for (int _i = 0; _i < 4; ++_i)                           \
    _Pragma("unroll") for (int _p = 0; _p < 2; ++_p)                         \
      _Pragma("unroll") for (int _kk = 0; _kk < 2; ++_kk)                    \
        acc[(mh)*4 + _i][(nh)*2 + _p] =                                      \
            __builtin_amdgcn_mfma_f32_16x16x32_bf16(                         \
                af[_i][_kk], bf[_p][_kk], acc[(mh)*4 + _i][(nh)*2 + _p],     \
                0, 0, 0);

#define MIDBAR  do { __builtin_amdgcn_s_barrier();                           \
                     asm volatile("s_waitcnt lgkmcnt(0)" ::: "memory");      \
                     __builtin_amdgcn_sched_barrier(0);                      \
                     __builtin_amdgcn_s_setprio(1); } while (0)
#define ENDBAR  do { __builtin_amdgcn_s_setprio(0);                          \
                     __builtin_amdgcn_s_barrier(); } while (0)

  f32x4 acc[8][4];
  #pragma unroll
  for (int i = 0; i < 8; ++i)
    #pragma unroll
    for (int j = 0; j < 4; ++j) acc[i][j] = f32x4{0.f, 0.f, 0.f, 0.f};

  STAGE(0, 0, 0, Abase, 0);
  STAGE(0, 1, 0, Bbase, 0);
  STAGE(0, 1, 1, Bbase, 0);
  STAGE(0, 0, 1, Abase, 0);
  STAGE(1, 0, 0, Abase, 64);
  STAGE(1, 1, 1, Bbase, 64);
  STAGE(1, 0, 1, Abase, 64);
  asm volatile("s_waitcnt vmcnt(6)" ::: "memory");
  __builtin_amdgcn_s_barrier();

  for (int t = 0; t < T; ++t) {
    const int cbuf = t & 1, nbuf = cbuf ^ 1;
    const int k1 = ((t + 1 < T) ? t + 1 : t + 1 - T) * 64;
    const int k2 = ((t + 2 < T) ? t + 2 : t + 2 - T) * 64;
    s16x8 af[4][2], bf[2][2];
    READ_A(af, cbuf, 0);
    READ_B(bf, cbuf, 0);
    STAGE(nbuf, 1, 0, Bbase, k1);
    asm volatile("s_waitcnt lgkmcnt(8)" ::: "memory");
    MIDBAR; MFMA_Q(0, 0); ENDBAR;
    READ_B(bf, cbuf, 1);
    STAGE(cbuf, 0, 0, Abase, k2);
    MIDBAR; MFMA_Q(0, 1); ENDBAR;
    READ_A(af, cbuf, 1);
    STAGE(cbuf, 1, 1, Bbase, k2);
    MIDBAR; MFMA_Q(1, 1); ENDBAR;
    READ_B(bf, cbuf, 0);
    STAGE(cbuf, 0, 1, Abase, k2);
    MIDBAR; MFMA_Q(1, 0);
    __builtin_amdgcn_s_setprio(0);
    asm volatile("s_waitcnt vmcnt(6)" ::: "memory");
    __builtin_amdgcn_s_barrier();
  }

  const int row0 = bm * 256, col0 = bn * 256;
  #pragma unroll
  for (int mi = 0; mi < 8; ++mi) {
    const int row = row0 + (mi >> 2) * 128 + wm * 64 + (mi & 3) * 16 + lk * 4;
    #pragma unroll
    for (int ni = 0; ni < 4; ++ni) {
      const int col = col0 + (ni >> 1) * 128 + wn * 32 + (ni & 1) * 16 + lr;
      const float bv = bias[col];
      #pragma unroll
      for (int r = 0; r < 4; ++r) {
        float v = acc[mi][ni][r] + bv;
        if (ACT == 0) v = fmaxf(v, 0.f);
        else          v = v / (1.f + __expf(-v));
        C[(size_t)(row + r) * N + col] = f2b(v);
      }
    }
  }
#undef STAGE
#undef READ_A
#undef READ_B
#undef MFMA_Q
#undef MIDBAR
#undef ENDBAR
}

// ---------------------------------------------------------------------------
// 128^2 GEMM, BK=64 dbuf, 64 KiB LDS, 2 blocks/CU (round-8, verified).
// ---------------------------------------------------------------------------
template<int ACT>
__global__ __launch_bounds__(256, 2) void gemm128(
    const ushort* __restrict__ A, const ushort* __restrict__ BT,
    const float* __restrict__ bias, ushort* __restrict__ C,
    int M, int N, int K)
{
  __shared__ __align__(16) ushort lds[32768];
  char* Lb = (char*)lds;

  const int tid = threadIdx.x, lane = tid & 63;
  const int w = tid >> 6;
  const int wm = w >> 1, wn = w & 1;

  const int gx  = gridDim.x;
  const int nwg = gx * gridDim.y;
  const int wid = blockIdx.y * gx + blockIdx.x;
  const int q   = nwg >> 3;
  const int Lw  = (wid & 7) * q + (wid >> 3);
  const int bn  = Lw % gx;
  const int bm  = Lw / gx;

  const ushort* Abase = A  + (size_t)bm * 128 * K;
  const ushort* Bbase = BT + (size_t)bn * 128 * K;
  const int T = K >> 6;

  const int srow = tid >> 3;
  const int scol = (((tid & 7) ^ (srow & 7)) << 3);

#define STAGE128(buf, k0)                                                    \
  {                                                                          \
    _Pragma("unroll") for (int _j = 0; _j < 4; ++_j)                         \
      __builtin_amdgcn_global_load_lds(                                      \
          (gas_ptr)(Abase + (size_t)(_j * 32 + srow) * K + (k0) + scol),     \
          (las_ptr)(Lb + (buf) + _j * 4096 + tid * 16), 16, 0, 0);           \
    _Pragma("unroll") for (int _j = 0; _j < 4; ++_j)                         \
      __builtin_amdgcn_global_load_lds(                                      \
          (gas_ptr)(Bbase + (size_t)(_j * 32 + srow) * K + (k0) + scol),     \
          (las_ptr)(Lb + (buf) + 16384 + _j * 4096 + tid * 16), 16, 0, 0);   \
  }

  const int lr = lane & 15, lk = lane >> 4;

  f32x4 acc[4][4];
  #pragma unroll
  for (int f = 0; f < 4; ++f)
    #pragma unroll
    for (int p = 0; p < 4; ++p) acc[f][p] = f32x4{0.f, 0.f, 0.f, 0.f};

  STAGE128(0, 0);
  __syncthreads();

  for (int t = 0; t < T; ++t) {
    const int cb = (t & 1) << 15, nb = cb ^ 32768;
    if (t + 1 < T) STAGE128(nb, (t + 1) << 6);

    s16x8 af[4][2], bf[4][2];
    #pragma unroll
    for (int f = 0; f < 4; ++f)
      #pragma unroll
      for (int kk = 0; kk < 2; ++kk) {
        const int r = wm * 64 + f * 16 + lr;
        af[f][kk] = *(const s16x8*)(Lb + cb + r * 128
                                    + ((kk * 64 + lk * 16) ^ ((r & 7) << 4)));
      }
    #pragma unroll
    for (int p = 0; p < 4; ++p)
      #pragma unroll
      for (int kk = 0; kk < 2; ++kk) {
        const int r = wn * 64 + p * 16 + lr;
        bf[p][kk] = *(const s16x8*)(Lb + cb + 16384 + r * 128
                                    + ((kk * 64 + lk * 16) ^ ((r & 7) << 4)));
      }
    #pragma unroll
    for (int f = 0; f < 4; ++f)
      #pragma unroll
      for (int p = 0; p < 4; ++p)
        #pragma unroll
        for (int kk = 0; kk < 2; ++kk)
          acc[f][p] = __builtin_amdgcn_mfma_f32_16x16x32_bf16(
              af[f][kk], bf[p][kk], acc[f][p], 0, 0, 0);

    __syncthreads();
  }

  const int row0 = bm * 128 + wm * 64;
  const int col0 = bn * 128 + wn * 64;
  #pragma unroll
  for (int f = 0; f < 4; ++f) {
    const int row = row0 + f * 16 + lk * 4;
    #pragma unroll
    for (int p = 0; p < 4; ++p) {
      const int col = col0 + p * 16 + lr;
      const float bv = bias[col];
      #pragma unroll
      for (int r = 0; r < 4; ++r) {
        float v = acc[f][p][r] + bv;
        if (ACT == 0) v = fmaxf(v, 0.f);
        else          v = v / (1.f + __expf(-v));
        C[(size_t)(row + r) * N + col] = f2b(v);
      }
    }
  }
#undef STAGE128
}

// ---------------------------------------------------------------------------
// FUSED-MIX 128^2 GEMM: A'[g,:] = sum_r adj[b, i, r] * x[3b+r, :] computed
// during staging (g = 3b+i), C = act(A' @ BT^T + bias).
// Reg-staged A (loads -> fma -> ds_write to swizzled slot); B via
// global_load_lds (pre-swizzled source). One __syncthreads per tile
// (compiler drains vmcnt/lgkm -> correct by construction).
// M%128==0, N%128==0, K%64==0.
// ---------------------------------------------------------------------------
template<int ACT>
__global__ __launch_bounds__(256, 2) void gemm128m(
    const ushort* __restrict__ x,
    const float* __restrict__ Aa, const float* __restrict__ Ab2, int split,
    const ushort* __restrict__ BT, const float* __restrict__ bias,
    ushort* __restrict__ C, int M, int N, int K)
{
  __shared__ __align__(16) ushort lds[32768];
  char* Lb = (char*)lds;

  const int tid = threadIdx.x, lane = tid & 63;
  const int w = tid >> 6;
  const int wm = w >> 1, wn = w & 1;

  const int gx  = gridDim.x;
  const int nwg = gx * gridDim.y;
  const int wid = blockIdx.y * gx + blockIdx.x;
  const int q   = nwg >> 3;
  const int Lw  = (wid & 7) * q + (wid >> 3);
  const int bn  = Lw % gx;
  const int bm  = Lw / gx;

  const ushort* Bbase = BT + (size_t)bn * 128 * K;
  const int T = K >> 6;

  const int srow  = tid >> 3;                          // 0..31
  const int lin8  = (tid & 7) * 8;                     // linear col (elems)
  const int swz16 = ((tid & 7) ^ (srow & 7)) << 4;     // swizzled slot (bytes)
  const int swcol = ((tid & 7) ^ (srow & 7)) << 3;     // pre-swz src col (elems)

  // per-j sample + adjacency row (constant over K); j covers rows j*32+srow
  const ushort* xrow[4];
  float av[4][3];
  #pragma unroll
  for (int j = 0; j < 4; ++j) {
    const int g = bm * 128 + j * 32 + srow;
    const int b = g / 3;
    const int i = g - 3 * b;
    const float* ad = (b < split) ? (Aa + (size_t)b * 9 + i * 3)
                                  : (Ab2 + (size_t)(b - split) * 9 + i * 3);
    av[j][0] = ad[0]; av[j][1] = ad[1]; av[j][2] = ad[2];
    xrow[j] = x + (size_t)(3 * b) * K + lin8;
  }

#define STAGEB_M(buf, k0)                                                    \
  { _Pragma("unroll") for (int _j = 0; _j < 4; ++_j)                         \
      __builtin_amdgcn_global_load_lds(                                      \
          (gas_ptr)(Bbase + (size_t)(_j * 32 + srow) * K + (k0) + swcol),    \
          (las_ptr)(Lb + (buf) + 16384 + _j * 4096 + tid * 16), 16, 0, 0); }

  s16x8 xr[4][3];
#define LOADX(k0)                                                            \
  { _Pragma("unroll") for (int _j = 0; _j < 4; ++_j) {                       \
      const ushort* _xb = xrow[_j] + (k0);                                   \
      xr[_j][0] = *(const s16x8*)_xb;                                        \
      xr[_j][1] = *(const s16x8*)(_xb + K);                                  \
      xr[_j][2] = *(const s16x8*)(_xb + 2 * K); } }

#define WRITEX(buf)                                                          \
  { _Pragma("unroll") for (int _j = 0; _j < 4; ++_j) {                       \
      s16x8 _o;                                                              \
      _Pragma("unroll") for (int _e = 0; _e < 8; ++_e)                       \
        _o[_e] = (short)f2b(av[_j][0] * b2f((ushort)xr[_j][0][_e])           \
                          + av[_j][1] * b2f((ushort)xr[_j][1][_e])           \
                          + av[_j][2] * b2f((ushort)xr[_j][2][_e]));         \
      *(s16x8*)(Lb + (buf) + _j * 4096 + srow * 128 + swz16) = _o; } }

  const int lr = lane & 15, lk = lane >> 4;

  f32x4 acc[4][4];
  #pragma unroll
  for (int f = 0; f < 4; ++f)
    #pragma unroll
    for (int p = 0; p < 4; ++p) acc[f][p] = f32x4{0.f, 0.f, 0.f, 0.f};

  // prologue: tile 0 (compiler inserts vmcnt wait before WRITEX's xr use)
  LOADX(0);
  STAGEB_M(0, 0);
  WRITEX(0);
  __syncthreads();

  for (int t = 0; t < T; ++t) {
    const int cb = (t & 1) << 15, nb = cb ^ 32768;
    const bool hn = (t + 1 < T);
    if (hn) { STAGEB_M(nb, (t + 1) << 6); LOADX((t + 1) << 6); }

    s16x8 af[4][2], bf[4][2];
    #pragma unroll
    for (int f = 0; f < 4; ++f)
      #pragma unroll
      for (int kk = 0; kk < 2; ++kk) {
        const int r = wm * 64 + f * 16 + lr;
        af[f][kk] = *(const s16x8*)(Lb + cb + r * 128
                                    + ((kk * 64 + lk * 16) ^ ((r & 7) << 4)));
      }
    #pragma unroll
    for (int p = 0; p < 4; ++p)
      #pragma unroll
      for (int kk = 0; kk < 2; ++kk) {
        const int r = wn * 64 + p * 16 + lr;
        bf[p][kk] = *(const s16x8*)(Lb + cb + 16384 + r * 128
                                    + ((kk * 64 + lk * 16) ^ ((r & 7) << 4)));
      }
    #pragma unroll
    for (int f = 0; f < 4; ++f)
      #pragma unroll
      for (int p = 0; p < 4; ++p)
        #pragma unroll
        for (int kk = 0; kk < 2; ++kk)
          acc[f][p] = __builtin_amdgcn_mfma_f32_16x16x32_bf16(
              af[f][kk], bf[p][kk], acc[f][p], 0, 0, 0);

    if (hn) WRITEX(nb);   // nb readers all passed last barrier; A/B regions disjoint
    __syncthreads();
  }

  const int row0 = bm * 128 + wm * 64;
  const int col0 = bn * 128 + wn * 64;
  #pragma unroll
  for (int f = 0; f < 4; ++f) {
    const int row = row0 + f * 16 + lk * 4;
    #pragma unroll
    for (int p = 0; p < 4; ++p) {
      const int col = col0 + p * 16 + lr;
      const float bv = bias[col];
      #pragma unroll
      for (int r = 0; r < 4; ++r) {
        float v = acc[f][p][r] + bv;
        if (ACT == 0) v = fmaxf(v, 0.f);
        else          v = v / (1.f + __expf(-v));
        C[(size_t)(row + r) * N + col] = f2b(v);
      }
    }
  }
#undef STAGEB_M
#undef LOADX
#undef WRITEX
}

// ---------------------------------------------------------------------------
__global__ void trans_conv(const float* __restrict__ W, ushort* __restrict__ WT,
                           int K, int N, int Kpad)
{
  __shared__ float tile[32][33];
  const int n0 = blockIdx.x * 32, k0 = blockIdx.y * 32;
  const int tx = threadIdx.x, ty = threadIdx.y;
  #pragma unroll
  for (int r = 0; r < 4; r++) {
    const int k = k0 + ty + r * 8;
    tile[ty + r * 8][tx] = (k < K) ? W[(size_t)k * N + n0 + tx] : 0.f;
  }
  __syncthreads();
  #pragma unroll
  for (int r = 0; r < 4; r++) {
    const int n = n0 + ty + r * 8;
    WT[(size_t)n * Kpad + k0 + tx] = f2b(tile[tx][ty + r * 8]);
  }
}

__global__ void conv_pad(const float* __restrict__ in, ushort* __restrict__ out,
                         int R, int Cin, int Cpad)
{
  const int gid = blockIdx.x * 256 + threadIdx.x;
  if (gid >= R * Cpad) return;
  const int r = gid / Cpad, c = gid - r * Cpad;
  out[gid] = (c < Cin) ? f2b(in[(size_t)r * Cin + c]) : (ushort)0;
}

// ---------------------------------------------------------------------------
DEV void ln_row(const ushort* __restrict__ in, const float* __restrict__ gamma,
                const float* __restrict__ beta, ushort* __restrict__ outp,
                int tid, float* red)
{
  s16x4 v = *(const s16x4*)&in[tid * 4];
  const float x0 = b2f((ushort)v[0]), x1 = b2f((ushort)v[1]);
  const float x2 = b2f((ushort)v[2]), x3 = b2f((ushort)v[3]);
  float s = x0 + x1 + x2 + x3;
  float qq = x0 * x0 + x1 * x1 + x2 * x2 + x3 * x3;
  #pragma unroll
  for (int o = 32; o > 0; o >>= 1) { s += __shfl_down(s, o); qq += __shfl_down(qq, o); }
  const int wv = tid >> 6, lane = tid & 63;
  __syncthreads();
  if (lane == 0) { red[wv] = s; red[4 + wv] = qq; }
  __syncthreads();
  s  = red[0] + red[1] + red[2] + red[3];
  qq = red[4] + red[5] + red[6] + red[7];
  const float m   = s * (1.f / 1024.f);
  const float var = qq * (1.f / 1024.f) - m * m;
  const float rs  = rsqrtf(var + 1e-3f);
  const int c = tid * 4;
  s16x4 o;
  o[0] = (short)f2b(gamma[c + 0] * ((x0 - m) * rs) + beta[c + 0]);
  o[1] = (short)f2b(gamma[c + 1] * ((x1 - m) * rs) + beta[c + 1]);
  o[2] = (short)f2b(gamma[c + 2] * ((x2 - m) * rs) + beta[c + 2]);
  o[3] = (short)f2b(gamma[c + 3] * ((x3 - m) * rs) + beta[c + 3]);
  *(s16x4*)&outp[c] = o;
}

__global__ void ln_te(const ushort* __restrict__ in, const float* __restrict__ g,
                      const float* __restrict__ b, ushort* __restrict__ out)
{
  __shared__ float red[8];
  ln_row(in + (size_t)blockIdx.x * 1024, g, b,
         out + (size_t)blockIdx.x * 1024, threadIdx.x, red);
}

__global__ void assembleX(const int* __restrict__ ta, const int* __restrict__ tb,
                          int split, const ushort* __restrict__ tetab,
                          const ushort* __restrict__ ge, const ushort* __restrict__ ce,
                          const float* __restrict__ gG, const float* __restrict__ gB,
                          const float* __restrict__ cG, const float* __restrict__ cB,
                          ushort* __restrict__ X)
{
  __shared__ float red[8];
  const int b = blockIdx.x, tid = threadIdx.x;
  const int tt = (b < split) ? ta[b] : tb[b - split];
  *(s16x4*)&X[(size_t)b * 3072 + tid * 4] =
      *(const s16x4*)&tetab[(size_t)tt * 1024 + tid * 4];
  ln_row(ge + (size_t)b * 1024, gG, gB, X + (size_t)b * 3072 + 1024, tid, red);
  ln_row(ce + (size_t)b * 1024, cG, cB, X + (size_t)b * 3072 + 2048, tid, red);
}

// ---------------------------------------------------------------------------
__global__ void zloss_k(const ushort* __restrict__ z1, const ushort* __restrict__ z2,
                        float* __restrict__ out, int n8)
{
  const int gid = blockIdx.x * 256 + threadIdx.x;
  if (gid >= n8) return;
  const size_t i = (size_t)gid * 8;
  s16x8 a = *(const s16x8*)&z1[i];
  s16x8 b = *(const s16x8*)&z2[i];
  f32x4 o0, o1;
  #pragma unroll
  for (int e = 0; e < 4; e++) {
    float d0 = b2f((ushort)a[e]) - b2f((ushort)b[e]);
    float d1 = b2f((ushort)a[e + 4]) - b2f((ushort)b[e + 4]);
    o0[e] = d0 * d0; o1[e] = d1 * d1;
  }
  *(f32x4*)&out[i] = o0; *(f32x4*)&out[i + 4] = o1;
}

__global__ void xloss2_k(const ushort* __restrict__ X1, const ushort* __restrict__ Xh1,
                         const ushort* __restrict__ X2, const ushort* __restrict__ Xh2,
                         float* __restrict__ out, int n8)
{
  const int gid = blockIdx.x * 256 + threadIdx.x;
  if (gid >= n8) return;
  const size_t i = (size_t)gid * 8;
  s16x8 a1 = *(const s16x8*)&X1[i];
  s16x8 h1 = *(const s16x8*)&Xh1[i];
  s16x8 a2 = *(const s16x8*)&X2[i];
  s16x8 h2 = *(const s16x8*)&Xh2[i];
  f32x4 o0, o1;
  #pragma unroll
  for (int e = 0; e < 4; e++) {
    float d1a = b2f((ushort)a1[e])     - b2f((ushort)h1[e]);
    float d2a = b2f((ushort)a2[e])     - b2f((ushort)h2[e]);
    float d1b = b2f((ushort)a1[e + 4]) - b2f((ushort)h1[e + 4]);
    float d2b = b2f((ushort)a2[e + 4]) - b2f((ushort)h2[e + 4]);
    o0[e] = 0.5f * (d1a * d1a + d2a * d2a);
    o1[e] = 0.5f * (d1b * d1b + d2b * d2b);
  }
  *(f32x4*)&out[i] = o0; *(f32x4*)&out[i + 4] = o1;
}

// ---------------------------------------------------------------------------
extern "C" void kernel_launch(void* const* d_in, const int* in_sizes, int n_in,
                              void* d_out, int out_size, void* d_ws, size_t ws_size,
                              hipStream_t stream)
{
  const int B = 16384, S = 3 * B;
  const int*   t1 = (const int*)d_in[0];
  const float* g1 = (const float*)d_in[1];
  const float* c1 = (const float*)d_in[2];
  const float* A1 = (const float*)d_in[3];
  const int*   t2 = (const int*)d_in[4];
  const float* g2 = (const float*)d_in[5];
  const float* c2 = (const float*)d_in[6];
  const float* A2 = (const float*)d_in[7];
  const float* embed = (const float*)d_in[8];
  const float* Wt = (const float*)d_in[9];  const float* bt = (const float*)d_in[10];
  const float* Wg = (const float*)d_in[11]; const float* bg = (const float*)d_in[12];
  const float* Wc = (const float*)d_in[13]; const float* bc = (const float*)d_in[14];
  const float* lntg = (const float*)d_in[15]; const float* lntb = (const float*)d_in[16];
  const float* lngg = (const float*)d_in[17]; const float* lngb = (const float*)d_in[18];
  const float* lncg = (const float*)d_in[19]; const float* lncb = (const float*)d_in[20];
  const float* eW0 = (const float*)d_in[21]; const float* eb0 = (const float*)d_in[22];
  const float* eW1 = (const float*)d_in[23]; const float* eb1 = (const float*)d_in[24];
  const float* eW2 = (const float*)d_in[25]; const float* eb2 = (const float*)d_in[26];
  const float* dW0 = (const float*)d_in[27]; const float* db0 = (const float*)d_in[28];
  const float* dW1 = (const float*)d_in[29]; const float* db1 = (const float*)d_in[30];
  const float* dW2 = (const float*)d_in[31]; const float* db2 = (const float*)d_in[32];
  float* out = (float*)d_out;
  (void)in_sizes; (void)n_in; (void)out_size;

  char* ws = (char*)d_ws; size_t off = 0;
  auto alloc = [&](size_t bytes) -> void* {
    void* p = ws + off; off += (bytes + 255) & ~(size_t)255; return p;
  };
  ushort* WtT  = (ushort*)alloc((size_t)1024 * 1024 * 2);
  ushort* WgT  = (ushort*)alloc((size_t)1024 * 896 * 2);
  ushort* WcT  = (ushort*)alloc((size_t)1024 * 128 * 2);
  ushort* E0T  = (ushort*)alloc((size_t)1024 * 1024 * 2);
  ushort* E1T  = (ushort*)alloc((size_t)512 * 1024 * 2);
  ushort* E2T  = (ushort*)alloc((size_t)256 * 512 * 2);
  ushort* D0T  = (ushort*)alloc((size_t)512 * 256 * 2);
  ushort* D1T  = (ushort*)alloc((size_t)1024 * 512 * 2);
  ushort* D2T  = (ushort*)alloc((size_t)1024 * 1024 * 2);
  ushort* embB = (ushort*)alloc((size_t)128 * 1024 * 2);
  ushort* teraw= (ushort*)alloc((size_t)128 * 1024 * 2);
  ushort* tetab= (ushort*)alloc((size_t)128 * 1024 * 2);
  const size_t woff = off;

  // merged layout (preferred)
  ushort* G  = (ushort*)alloc((size_t)2 * B * 896 * 2);
  ushort* Cc = (ushort*)alloc((size_t)2 * B * 128 * 2);
  ushort* Z  = (ushort*)alloc((size_t)2 * S * 256 * 2);
  ushort* Xs = (ushort*)alloc((size_t)2 * S * 1024 * 2);
  ushort* b0 = (ushort*)alloc((size_t)2 * S * 1024 * 2);
  ushort* b1 = (ushort*)alloc((size_t)2 * S * 1024 * 2);
  const bool merged = (off <= ws_size);

  // fallback layout (per-branch)
  ushort *fG[2], *fC[2], *fZ[2], *fX[2], *fb0, *fb1, *fxh;
  if (!merged) {
    off = woff;
    fG[0] = (ushort*)alloc((size_t)B * 896 * 2);
    fG[1] = (ushort*)alloc((size_t)B * 896 * 2);
    fC[0] = (ushort*)alloc((size_t)B * 128 * 2);
    fC[1] = (ushort*)alloc((size_t)B * 128 * 2);
    fZ[0] = (ushort*)alloc((size_t)S * 256 * 2);
    fZ[1] = (ushort*)alloc((size_t)S * 256 * 2);
    fX[0] = (ushort*)alloc((size_t)S * 1024 * 2);
    fX[1] = (ushort*)alloc((size_t)S * 1024 * 2);
    fb0   = (ushort*)alloc((size_t)S * 1024 * 2);
    fb1   = (ushort*)alloc((size_t)S * 1024 * 2);
    fxh   = (ushort*)alloc((size_t)S * 1024 * 2);
  }

  const dim3 TB(32, 8);
  trans_conv<<<dim3(32, 32), TB, 0, stream>>>(Wt,  WtT, 1024, 1024, 1024);
  trans_conv<<<dim3(32, 28), TB, 0, stream>>>(Wg,  WgT,  772, 1024,  896);
  trans_conv<<<dim3(32,  4), TB, 0, stream>>>(Wc,  WcT,  100, 1024,  128);
  trans_conv<<<dim3(32, 32), TB, 0, stream>>>(eW0, E0T, 1024, 1024, 1024);
  trans_conv<<<dim3(16, 32), TB, 0, stream>>>(eW1, E1T, 1024,  512, 1024);
  trans_conv<<<dim3( 8, 16), TB, 0, stream>>>(eW2, E2T,  512,  256,  512);
  trans_conv<<<dim3(16,  8), TB, 0, stream>>>(dW0, D0T,  256,  512,  256);
  trans_conv<<<dim3(32, 16), TB, 0, stream>>>(dW1, D1T,  512, 1024,  512);
  trans_conv<<<dim3(32, 32), TB, 0, stream>>>(dW2, D2T, 1024, 1024, 1024);
  conv_pad<<<512, 256, 0, stream>>>(embed, embB, 128, 1024, 1024);
  gemm128<0><<<dim3(8, 1), 256, 0, stream>>>(embB, WtT, bt, teraw, 128, 1024, 1024);
  ln_te<<<128, 256, 0, stream>>>(teraw, lntg, lntb, tetab);

  const size_t ZLEN = (size_t)S * 256;
  const int n8x = S * 1024 / 8;

  // pipeline over nS samples (Ms = 3*nS rows); fused-mix GEMMs throughout.
  auto pipeline = [&](ushort* Gp, ushort* Cp, const int* ta, const int* tb,
                      const float* Aa, const float* Ab2, int split, int nS,
                      ushort* Xp, ushort* p0, ushort* p1, ushort* Zp, ushort* xh) {
    const int Ms = nS * 3;
    gemm256<0><<<dim3(4, nS / 256), 512, 0, stream>>>(Gp, WgT, bg, p0, nS, 1024, 896);
    gemm128<0><<<dim3(8, nS / 128), 256, 0, stream>>>(Cp, WcT, bc, p1, nS, 1024, 128);
    assembleX<<<nS, 256, 0, stream>>>(ta, tb, split, tetab, p0, p1,
                                      lngg, lngb, lncg, lncb, Xp);
    // encoder (relu): mix fused into A-staging
    gemm128m<0><<<dim3(8, Ms / 128), 256, 0, stream>>>(Xp, Aa, Ab2, split, E0T, eb0, p1, Ms, 1024, 1024);
    gemm128m<0><<<dim3(4, Ms / 128), 256, 0, stream>>>(p1, Aa, Ab2, split, E1T, eb1, p0, Ms, 512, 1024);
    gemm128m<0><<<dim3(2, Ms / 128), 256, 0, stream>>>(p0, Aa, Ab2, split, E2T, eb2, Zp, Ms, 256, 512);
    // decoder (silu)
    gemm128m<1><<<dim3(4, Ms / 128), 256, 0, stream>>>(Zp, Aa, Ab2, split, D0T, db0, p1, Ms, 512, 256);
    gemm128m<1><<<dim3(8, Ms / 128), 256, 0, stream>>>(p1, Aa, Ab2, split, D1T, db1, p0, Ms, 1024, 512);
    gemm128m<1><<<dim3(8, Ms / 128), 256, 0, stream>>>(p0, Aa, Ab2, split, D2T, db2, xh, Ms, 1024, 1024);
  };

  if (merged) {
    conv_pad<<<(B * 896 + 255) / 256, 256, 0, stream>>>(g1, G, B, 772, 896);
    conv_pad<<<(B * 896 + 255) / 256, 256, 0, stream>>>(g2, G + (size_t)B * 896, B, 772, 896);
    conv_pad<<<B * 128 / 256, 256, 0, stream>>>(c1, Cc, B, 100, 128);
    conv_pad<<<B * 128 / 256, 256, 0, stream>>>(c2, Cc + (size_t)B * 128, B, 100, 128);
    pipeline(G, Cc, t1, t2, A1, A2, B, 2 * B, Xs, b0, b1, Z, b1);
    xloss2_k<<<n8x / 256, 256, 0, stream>>>(
        Xs, b1, Xs + (size_t)S * 1024, b1 + (size_t)S * 1024, out + ZLEN, n8x);
    zloss_k<<<(int)(ZLEN / 8 / 256), 256, 0, stream>>>(Z, Z + ZLEN, out, (int)(ZLEN / 8));
  } else {
    for (int br = 0; br < 2; ++br) {
      conv_pad<<<(B * 896 + 255) / 256, 256, 0, stream>>>(br ? g2 : g1, fG[br], B, 772, 896);
      conv_pad<<<B * 128 / 256, 256, 0, stream>>>(br ? c2 : c1, fC[br], B, 100, 128);
      const int*   t    = br ? t2 : t1;
      const float* Aadj = br ? A2 : A1;
      pipeline(fG[br], fC[br], t, t, Aadj, Aadj, B, B,
               fX[br], fb0, fb1, fZ[br], br ? fb1 : fxh);
    }
    xloss2_k<<<n8x / 256, 256, 0, stream>>>(fX[0], fxh, fX[1], fb1, out + ZLEN, n8x);
    zloss_k<<<(int)(ZLEN / 8 / 256), 256, 0, stream>>>(fZ[0], fZ[1], out, (int)(ZLEN / 8));
  }
}

// Round 12
// 1422.113 us; speedup vs baseline: 1.3079x; 1.3079x over previous
//
#include <hip/hip_runtime.h>

// ---------------------------------------------------------------------------
// CMAPFeatureExtractor: twin-branch GCN autoencoder on MI355X (gfx950).
// Round 12: round-10 base (r11 fusion reverted: VALU-bound, -373us). New:
// (1) mix commuted across GEMM on contracting layers E1/E2 ((Ax)W = A(xW)):
//     GEMM writes raw (ACT=2), then mixact = relu(A*y + b) on the SMALLER
//     d_out side (saves ~300 MB HBM);
// (2) 9x trans_conv -> 1 dispatch, 5x conv_pad -> 1 dispatch (launch gaps).
// ---------------------------------------------------------------------------

typedef __attribute__((ext_vector_type(8))) short s16x8;   // 8 x bf16
typedef __attribute__((ext_vector_type(4))) short s16x4;   // 4 x bf16
typedef __attribute__((ext_vector_type(4))) float f32x4;

#define DEV static __device__ __forceinline__

DEV float b2f(ushort u) { return __builtin_bit_cast(float, (unsigned)u << 16); }
DEV ushort f2b(float f) {
  unsigned x = __builtin_bit_cast(unsigned, f);
  unsigned r = x + 0x7fffu + ((x >> 16) & 1u);   // RNE; inputs are finite
  return (ushort)(r >> 16);
}

typedef const __attribute__((address_space(1))) void* gas_ptr;
typedef __attribute__((address_space(3))) void* las_ptr;

// ---------------------------------------------------------------------------
// 256^2 GEMM, 4-phase fragment-reuse schedule (round-7, verified).
// ACT: 0 relu, 1 silu, 2 identity (raw, no bias).
// M%256==0, N%256==0, K%128==0. 8 waves, wave-tile 128x64.
// ---------------------------------------------------------------------------
template<int ACT>
__global__ __launch_bounds__(512, 2) void gemm256(
    const ushort* __restrict__ A, const ushort* __restrict__ BT,
    const float* __restrict__ bias, ushort* __restrict__ C,
    int M, int N, int K)
{
  __shared__ __align__(16) ushort ldsbuf[65536];   // 128 KiB
  char* Lb = (char*)ldsbuf;

  const int tid = threadIdx.x, lane = tid & 63, w = tid >> 6;
  const int wm = w >> 2, wn = w & 3;

  const int gx  = gridDim.x;
  const int nwg = gx * gridDim.y;
  const int wid = blockIdx.y * gx + blockIdx.x;
  const int q   = nwg >> 3;
  const int Lw  = (wid & 7) * q + (wid >> 3);
  const int bn  = Lw % gx;
  const int bm  = Lw / gx;

  const ushort* Abase = A  + (size_t)bm * 256 * K;
  const ushort* Bbase = BT + (size_t)bn * 256 * K;
  const int T = K >> 6;

  const int srow = w * 8 + (lane >> 3);
  const int scol = (((lane & 7) ^ (lane >> 3)) << 3);

#define STAGE(buf, m, half, Gb, k0)                                          \
  {                                                                          \
    _Pragma("unroll") for (int _j = 0; _j < 2; ++_j) {                       \
      const ushort* _src = (Gb) + (size_t)((half)*128 + _j*64 + srow) * K    \
                           + (k0) + scol;                                    \
      ushort* _dst = (ushort*)(Lb + ((buf)*2 + (m)) * 32768                  \
                               + ((half)*128 + _j*64 + w*8) * 128);          \
      __builtin_amdgcn_global_load_lds((gas_ptr)_src, (las_ptr)_dst, 16,0,0);\
    }                                                                        \
  }

  const int lr = lane & 15, lk = lane >> 4;

#define READ_A(dst, c, mh)                                                   \
  _Pragma("unroll") for (int _i = 0; _i < 4; ++_i)                           \
    _Pragma("unroll") for (int _kk = 0; _kk < 2; ++_kk) {                    \
      const int _r   = (mh)*128 + wm*64 + _i*16 + lr;                        \
      const int _cbb = _kk*64 + lk*16;                                       \
      dst[_i][_kk] = *(const s16x8*)(Lb + ((c)*2 + 0)*32768 + _r*128         \
                                     + (_cbb ^ ((_r & 7) << 4)));            \
    }
#define READ_B(dst, c, nh)                                                   \
  _Pragma("unroll") for (int _p = 0; _p < 2; ++_p)                           \
    _Pragma("unroll") for (int _kk = 0; _kk < 2; ++_kk) {                    \
      const int _r   = (nh)*128 + wn*32 + _p*16 + lr;                        \
      const int _cbb = _kk*64 + lk*16;                                       \
      dst[_p][_kk] = *(const s16x8*)(Lb + ((c)*2 + 1)*32768 + _r*128         \
                                     + (_cbb ^ ((_r & 7) << 4)));            \
    }

#define MFMA_Q(mh, nh)                                                       \
  _Pragma("unroll") for (int _i = 0; _i < 4; ++_i)                           \
    _Pragma("unroll") for (int _p = 0; _p < 2; ++_p)                         \
      _Pragma("unroll") for (int _kk = 0; _kk < 2; ++_kk)                    \
        acc[(mh)*4 + _i][(nh)*2 + _p] =                                      \
            __builtin_amdgcn_mfma_f32_16x16x32_bf16(                         \
                af[_i][_kk], bf[_p][_kk], acc[(mh)*4 + _i][(nh)*2 + _p],     \
                0, 0, 0);

#define MIDBAR  do { __builtin_amdgcn_s_barrier();                           \
                     asm volatile("s_waitcnt lgkmcnt(0)" ::: "memory");      \
                     __builtin_amdgcn_sched_barrier(0);                      \
                     __builtin_amdgcn_s_setprio(1); } while (0)
#define ENDBAR  do { __builtin_amdgcn_s_setprio(0);                          \
                     __builtin_amdgcn_s_barrier(); } while (0)

  f32x4 acc[8][4];
  #pragma unroll
  for (int i = 0; i < 8; ++i)
    #pragma unroll
    for (int j = 0; j < 4; ++j) acc[i][j] = f32x4{0.f, 0.f, 0.f, 0.f};

  STAGE(0, 0, 0, Abase, 0);
  STAGE(0, 1, 0, Bbase, 0);
  STAGE(0, 1, 1, Bbase, 0);
  STAGE(0, 0, 1, Abase, 0);
  STAGE(1, 0, 0, Abase, 64);
  STAGE(1, 1, 1, Bbase, 64);
  STAGE(1, 0, 1, Abase, 64);
  asm volatile("s_waitcnt vmcnt(6)" ::: "memory");
  __builtin_amdgcn_s_barrier();

  for (int t = 0; t < T; ++t) {
    const int cbuf = t & 1, nbuf = cbuf ^ 1;
    const int k1 = ((t + 1 < T) ? t + 1 : t + 1 - T) * 64;
    const int k2 = ((t + 2 < T) ? t + 2 : t + 2 - T) * 64;
    s16x8 af[4][2], bf[2][2];
    READ_A(af, cbuf, 0);
    READ_B(bf, cbuf, 0);
    STAGE(nbuf, 1, 0, Bbase, k1);
    asm volatile("s_waitcnt lgkmcnt(8)" ::: "memory");
    MIDBAR; MFMA_Q(0, 0); ENDBAR;
    READ_B(bf, cbuf, 1);
    STAGE(cbuf, 0, 0, Abase, k2);
    MIDBAR; MFMA_Q(0, 1); ENDBAR;
    READ_A(af, cbuf, 1);
    STAGE(cbuf, 1, 1, Bbase, k2);
    MIDBAR; MFMA_Q(1, 1); ENDBAR;
    READ_B(bf, cbuf, 0);
    STAGE(cbuf, 0, 1, Abase, k2);
    MIDBAR; MFMA_Q(1, 0);
    __builtin_amdgcn_s_setprio(0);
    asm volatile("s_waitcnt vmcnt(6)" ::: "memory");
    __builtin_amdgcn_s_barrier();
  }

  const int row0 = bm * 256, col0 = bn * 256;
  #pragma unroll
  for (int mi = 0; mi < 8; ++mi) {
    const int row = row0 + (mi >> 2) * 128 + wm * 64 + (mi & 3) * 16 + lk * 4;
    #pragma unroll
    for (int ni = 0; ni < 4; ++ni) {
      const int col = col0 + (ni >> 1) * 128 + wn * 32 + (ni & 1) * 16 + lr;
      const float bv = (ACT == 2) ? 0.f : bias[col];
      #pragma unroll
      for (int r = 0; r < 4; ++r) {
        float v = acc[mi][ni][r] + bv;
        if (ACT == 0)      v = fmaxf(v, 0.f);
        else if (ACT == 1) v = v / (1.f + __expf(-v));
        C[(size_t)(row + r) * N + col] = f2b(v);
      }
    }
  }
#undef STAGE
#undef READ_A
#undef READ_B
#undef MFMA_Q
#undef MIDBAR
#undef ENDBAR
}

// ---------------------------------------------------------------------------
// 128^2 GEMM, BK=64 dbuf, 64 KiB LDS, 2 blocks/CU (round-8, verified).
// ACT: 0 relu, 1 silu, 2 identity (raw, no bias).
// ---------------------------------------------------------------------------
template<int ACT>
__global__ __launch_bounds__(256, 2) void gemm128(
    const ushort* __restrict__ A, const ushort* __restrict__ BT,
    const float* __restrict__ bias, ushort* __restrict__ C,
    int M, int N, int K)
{
  __shared__ __align__(16) ushort lds[32768];
  char* Lb = (char*)lds;

  const int tid = threadIdx.x, lane = tid & 63;
  const int w = tid >> 6;
  const int wm = w >> 1, wn = w & 1;

  const int gx  = gridDim.x;
  const int nwg = gx * gridDim.y;
  const int wid = blockIdx.y * gx + blockIdx.x;
  const int q   = nwg >> 3;
  const int Lw  = (wid & 7) * q + (wid >> 3);
  const int bn  = Lw % gx;
  const int bm  = Lw / gx;

  const ushort* Abase = A  + (size_t)bm * 128 * K;
  const ushort* Bbase = BT + (size_t)bn * 128 * K;
  const int T = K >> 6;

  const int srow = tid >> 3;
  const int scol = (((tid & 7) ^ (srow & 7)) << 3);

#define STAGE128(buf, k0)                                                    \
  {                                                                          \
    _Pragma("unroll") for (int _j = 0; _j < 4; ++_j)                         \
      __builtin_amdgcn_global_load_lds(                                      \
          (gas_ptr)(Abase + (size_t)(_j * 32 + srow) * K + (k0) + scol),     \
          (las_ptr)(Lb + (buf) + _j * 4096 + tid * 16), 16, 0, 0);           \
    _Pragma("unroll") for (int _j = 0; _j < 4; ++_j)                         \
      __builtin_amdgcn_global_load_lds(                                      \
          (gas_ptr)(Bbase + (size_t)(_j * 32 + srow) * K + (k0) + scol),     \
          (las_ptr)(Lb + (buf) + 16384 + _j * 4096 + tid * 16), 16, 0, 0);   \
  }

  const int lr = lane & 15, lk = lane >> 4;

  f32x4 acc[4][4];
  #pragma unroll
  for (int f = 0; f < 4; ++f)
    #pragma unroll
    for (int p = 0; p < 4; ++p) acc[f][p] = f32x4{0.f, 0.f, 0.f, 0.f};

  STAGE128(0, 0);
  __syncthreads();

  for (int t = 0; t < T; ++t) {
    const int cb = (t & 1) << 15, nb = cb ^ 32768;
    if (t + 1 < T) STAGE128(nb, (t + 1) << 6);

    s16x8 af[4][2], bf[4][2];
    #pragma unroll
    for (int f = 0; f < 4; ++f)
      #pragma unroll
      for (int kk = 0; kk < 2; ++kk) {
        const int r = wm * 64 + f * 16 + lr;
        af[f][kk] = *(const s16x8*)(Lb + cb + r * 128
                                    + ((kk * 64 + lk * 16) ^ ((r & 7) << 4)));
      }
    #pragma unroll
    for (int p = 0; p < 4; ++p)
      #pragma unroll
      for (int kk = 0; kk < 2; ++kk) {
        const int r = wn * 64 + p * 16 + lr;
        bf[p][kk] = *(const s16x8*)(Lb + cb + 16384 + r * 128
                                    + ((kk * 64 + lk * 16) ^ ((r & 7) << 4)));
      }
    #pragma unroll
    for (int f = 0; f < 4; ++f)
      #pragma unroll
      for (int p = 0; p < 4; ++p)
        #pragma unroll
        for (int kk = 0; kk < 2; ++kk)
          acc[f][p] = __builtin_amdgcn_mfma_f32_16x16x32_bf16(
              af[f][kk], bf[p][kk], acc[f][p], 0, 0, 0);

    __syncthreads();
  }

  const int row0 = bm * 128 + wm * 64;
  const int col0 = bn * 128 + wn * 64;
  #pragma unroll
  for (int f = 0; f < 4; ++f) {
    const int row = row0 + f * 16 + lk * 4;
    #pragma unroll
    for (int p = 0; p < 4; ++p) {
      const int col = col0 + p * 16 + lr;
      const float bv = (ACT == 2) ? 0.f : bias[col];
      #pragma unroll
      for (int r = 0; r < 4; ++r) {
        float v = acc[f][p][r] + bv;
        if (ACT == 0)      v = fmaxf(v, 0.f);
        else if (ACT == 1) v = v / (1.f + __expf(-v));
        C[(size_t)(row + r) * N + col] = f2b(v);
      }
    }
  }
#undef STAGE128
}

// ---------------------------------------------------------------------------
// merged weight transpose+convert: 9 matrices in one dispatch (blockIdx.z)
// ---------------------------------------------------------------------------
struct TP { const float* W; ushort* WT; int K, N, Kpad; };
struct TP9 { TP t[9]; };

__global__ void trans_all(TP9 ps)
{
  __shared__ float tile[32][33];
  const TP tp = ps.t[blockIdx.z];
  const int n0 = blockIdx.x * 32, k0 = blockIdx.y * 32;
  if (n0 >= tp.N || k0 >= tp.Kpad) return;
  const int tx = threadIdx.x, ty = threadIdx.y;   // (32,8)
  #pragma unroll
  for (int r = 0; r < 4; r++) {
    const int k = k0 + ty + r * 8;
    tile[ty + r * 8][tx] = (k < tp.K) ? tp.W[(size_t)k * tp.N + n0 + tx] : 0.f;
  }
  __syncthreads();
  #pragma unroll
  for (int r = 0; r < 4; r++) {
    const int n = n0 + ty + r * 8;
    tp.WT[(size_t)n * tp.Kpad + k0 + tx] = f2b(tile[tx][ty + r * 8]);
  }
}

// merged f32 -> bf16 pad: 5 segments in one grid-stride dispatch
struct CP { const float* in; ushort* out; int Cin, Cpad; size_t total; };
struct CP5 { CP s[5]; size_t cum[5]; };

__global__ void conv_all(CP5 ps, size_t grand)
{
  for (size_t gid = (size_t)blockIdx.x * 256 + threadIdx.x; gid < grand;
       gid += (size_t)gridDim.x * 256) {
    int si = 0;
    #pragma unroll
    for (int k = 1; k < 5; ++k) si += (gid >= ps.cum[k - 1]);
    const CP sp = ps.s[si];
    const size_t l = gid - (si ? ps.cum[si - 1] : 0);
    const size_t r = l / sp.Cpad;
    const int c = (int)(l - r * sp.Cpad);
    sp.out[l] = (c < sp.Cin) ? f2b(sp.in[r * sp.Cin + c]) : (ushort)0;
  }
}

// ---------------------------------------------------------------------------
DEV void ln_row(const ushort* __restrict__ in, const float* __restrict__ gamma,
                const float* __restrict__ beta, ushort* __restrict__ outp,
                int tid, float* red)
{
  s16x4 v = *(const s16x4*)&in[tid * 4];
  const float x0 = b2f((ushort)v[0]), x1 = b2f((ushort)v[1]);
  const float x2 = b2f((ushort)v[2]), x3 = b2f((ushort)v[3]);
  float s = x0 + x1 + x2 + x3;
  float qq = x0 * x0 + x1 * x1 + x2 * x2 + x3 * x3;
  #pragma unroll
  for (int o = 32; o > 0; o >>= 1) { s += __shfl_down(s, o); qq += __shfl_down(qq, o); }
  const int wv = tid >> 6, lane = tid & 63;
  __syncthreads();
  if (lane == 0) { red[wv] = s; red[4 + wv] = qq; }
  __syncthreads();
  s  = red[0] + red[1] + red[2] + red[3];
  qq = red[4] + red[5] + red[6] + red[7];
  const float m   = s * (1.f / 1024.f);
  const float var = qq * (1.f / 1024.f) - m * m;
  const float rs  = rsqrtf(var + 1e-3f);
  const int c = tid * 4;
  s16x4 o;
  o[0] = (short)f2b(gamma[c + 0] * ((x0 - m) * rs) + beta[c + 0]);
  o[1] = (short)f2b(gamma[c + 1] * ((x1 - m) * rs) + beta[c + 1]);
  o[2] = (short)f2b(gamma[c + 2] * ((x2 - m) * rs) + beta[c + 2]);
  o[3] = (short)f2b(gamma[c + 3] * ((x3 - m) * rs) + beta[c + 3]);
  *(s16x4*)&outp[c] = o;
}

__global__ void ln_te(const ushort* __restrict__ in, const float* __restrict__ g,
                      const float* __restrict__ b, ushort* __restrict__ out)
{
  __shared__ float red[8];
  ln_row(in + (size_t)blockIdx.x * 1024, g, b,
         out + (size_t)blockIdx.x * 1024, threadIdx.x, red);
}

__global__ void assembleX(const int* __restrict__ ta, const int* __restrict__ tb,
                          int split, const ushort* __restrict__ tetab,
                          const ushort* __restrict__ ge, const ushort* __restrict__ ce,
                          const float* __restrict__ gG, const float* __restrict__ gB,
                          const float* __restrict__ cG, const float* __restrict__ cB,
                          ushort* __restrict__ X)
{
  __shared__ float red[8];
  const int b = blockIdx.x, tid = threadIdx.x;
  const int tt = (b < split) ? ta[b] : tb[b - split];
  *(s16x4*)&X[(size_t)b * 3072 + tid * 4] =
      *(const s16x4*)&tetab[(size_t)tt * 1024 + tid * 4];
  ln_row(ge + (size_t)b * 1024, gG, gB, X + (size_t)b * 3072 + 1024, tid, red);
  ln_row(ce + (size_t)b * 1024, cG, cB, X + (size_t)b * 3072 + 2048, tid, red);
}

// ---------------------------------------------------------------------------
// per-sample 3x3 adjacency mix (plain, round-10): out[b,i,:]=sum_j a_ij x[b,j,:]
// ---------------------------------------------------------------------------
__global__ void mix3(const ushort* __restrict__ x,
                     const float* __restrict__ Aa, const float* __restrict__ Ab2,
                     int split, ushort* __restrict__ out, int d, int lg, int nB)
{
  const int gid = blockIdx.x * 256 + threadIdx.x;
  const int b = gid >> lg;
  if (b >= nB) return;
  const int c8 = (gid & ((1 << lg) - 1)) << 3;
  const ushort* xb = x   + (size_t)b * 3 * d + c8;
  ushort*       ob = out + (size_t)b * 3 * d + c8;
  s16x8 x0 = *(const s16x8*)xb;
  s16x8 x1 = *(const s16x8*)(xb + d);
  s16x8 x2 = *(const s16x8*)(xb + 2 * d);
  float f0[8], f1[8], f2[8];
  #pragma unroll
  for (int e = 0; e < 8; e++) {
    f0[e] = b2f((ushort)x0[e]); f1[e] = b2f((ushort)x1[e]); f2[e] = b2f((ushort)x2[e]);
  }
  const float* Ab = (b < split) ? (Aa + (size_t)b * 9)
                                : (Ab2 + (size_t)(b - split) * 9);
  #pragma unroll
  for (int j = 0; j < 3; j++) {
    const float a0 = Ab[j * 3], a1 = Ab[j * 3 + 1], a2 = Ab[j * 3 + 2];
    s16x8 o;
    #pragma unroll
    for (int e = 0; e < 8; e++)
      o[e] = (short)f2b(a0 * f0[e] + a1 * f1[e] + a2 * f2[e]);
    *(s16x8*)(ob + j * d) = o;
  }
}

// mix + bias + relu (commuted layers): out[b,i,:] = relu(sum_j a_ij y[b,j,:] + bias)
__global__ void mixact(const ushort* __restrict__ y,
                       const float* __restrict__ Aa, const float* __restrict__ Ab2,
                       int split, const float* __restrict__ bias,
                       ushort* __restrict__ out, int d, int lg, int nB)
{
  const int gid = blockIdx.x * 256 + threadIdx.x;
  const int b = gid >> lg;
  if (b >= nB) return;
  const int c8 = (gid & ((1 << lg) - 1)) << 3;
  const ushort* yb = y   + (size_t)b * 3 * d + c8;
  ushort*       ob = out + (size_t)b * 3 * d + c8;
  s16x8 y0 = *(const s16x8*)yb;
  s16x8 y1 = *(const s16x8*)(yb + d);
  s16x8 y2 = *(const s16x8*)(yb + 2 * d);
  f32x4 bv0 = *(const f32x4*)&bias[c8];
  f32x4 bv1 = *(const f32x4*)&bias[c8 + 4];
  float f0[8], f1[8], f2[8];
  #pragma unroll
  for (int e = 0; e < 8; e++) {
    f0[e] = b2f((ushort)y0[e]); f1[e] = b2f((ushort)y1[e]); f2[e] = b2f((ushort)y2[e]);
  }
  const float* Ab = (b < split) ? (Aa + (size_t)b * 9)
                                : (Ab2 + (size_t)(b - split) * 9);
  #pragma unroll
  for (int j = 0; j < 3; j++) {
    const float a0 = Ab[j * 3], a1 = Ab[j * 3 + 1], a2 = Ab[j * 3 + 2];
    s16x8 o;
    #pragma unroll
    for (int e = 0; e < 8; e++) {
      const float bb = (e < 4) ? bv0[e] : bv1[e - 4];
      o[e] = (short)f2b(fmaxf(a0 * f0[e] + a1 * f1[e] + a2 * f2[e] + bb, 0.f));
    }
    *(s16x8*)(ob + j * d) = o;
  }
}

// ---------------------------------------------------------------------------
__global__ void zloss_k(const ushort* __restrict__ z1, const ushort* __restrict__ z2,
                        float* __restrict__ out, int n8)
{
  const int gid = blockIdx.x * 256 + threadIdx.x;
  if (gid >= n8) return;
  const size_t i = (size_t)gid * 8;
  s16x8 a = *(const s16x8*)&z1[i];
  s16x8 b = *(const s16x8*)&z2[i];
  f32x4 o0, o1;
  #pragma unroll
  for (int e = 0; e < 4; e++) {
    float d0 = b2f((ushort)a[e]) - b2f((ushort)b[e]);
    float d1 = b2f((ushort)a[e + 4]) - b2f((ushort)b[e + 4]);
    o0[e] = d0 * d0; o1[e] = d1 * d1;
  }
  *(f32x4*)&out[i] = o0; *(f32x4*)&out[i + 4] = o1;
}

__global__ void xloss2_k(const ushort* __restrict__ X1, const ushort* __restrict__ Xh1,
                         const ushort* __restrict__ X2, const ushort* __restrict__ Xh2,
                         float* __restrict__ out, int n8)
{
  const int gid = blockIdx.x * 256 + threadIdx.x;
  if (gid >= n8) return;
  const size_t i = (size_t)gid * 8;
  s16x8 a1 = *(const s16x8*)&X1[i];
  s16x8 h1 = *(const s16x8*)&Xh1[i];
  s16x8 a2 = *(const s16x8*)&X2[i];
  s16x8 h2 = *(const s16x8*)&Xh2[i];
  f32x4 o0, o1;
  #pragma unroll
  for (int e = 0; e < 4; e++) {
    float d1a = b2f((ushort)a1[e])     - b2f((ushort)h1[e]);
    float d2a = b2f((ushort)a2[e])     - b2f((ushort)h2[e]);
    float d1b = b2f((ushort)a1[e + 4]) - b2f((ushort)h1[e + 4]);
    float d2b = b2f((ushort)a2[e + 4]) - b2f((ushort)h2[e + 4]);
    o0[e] = 0.5f * (d1a * d1a + d2a * d2a);
    o1[e] = 0.5f * (d1b * d1b + d2b * d2b);
  }
  *(f32x4*)&out[i] = o0; *(f32x4*)&out[i + 4] = o1;
}

// ---------------------------------------------------------------------------
extern "C" void kernel_launch(void* const* d_in, const int* in_sizes, int n_in,
                              void* d_out, int out_size, void* d_ws, size_t ws_size,
                              hipStream_t stream)
{
  const int B = 16384, S = 3 * B;
  const int*   t1 = (const int*)d_in[0];
  const float* g1 = (const float*)d_in[1];
  const float* c1 = (const float*)d_in[2];
  const float* A1 = (const float*)d_in[3];
  const int*   t2 = (const int*)d_in[4];
  const float* g2 = (const float*)d_in[5];
  const float* c2 = (const float*)d_in[6];
  const float* A2 = (const float*)d_in[7];
  const float* embed = (const float*)d_in[8];
  const float* Wt = (const float*)d_in[9];  const float* bt = (const float*)d_in[10];
  const float* Wg = (const float*)d_in[11]; const float* bg = (const float*)d_in[12];
  const float* Wc = (const float*)d_in[13]; const float* bc = (const float*)d_in[14];
  const float* lntg = (const float*)d_in[15]; const float* lntb = (const float*)d_in[16];
  const float* lngg = (const float*)d_in[17]; const float* lngb = (const float*)d_in[18];
  const float* lncg = (const float*)d_in[19]; const float* lncb = (const float*)d_in[20];
  const float* eW0 = (const float*)d_in[21]; const float* eb0 = (const float*)d_in[22];
  const float* eW1 = (const float*)d_in[23]; const float* eb1 = (const float*)d_in[24];
  const float* eW2 = (const float*)d_in[25]; const float* eb2 = (const float*)d_in[26];
  const float* dW0 = (const float*)d_in[27]; const float* db0 = (const float*)d_in[28];
  const float* dW1 = (const float*)d_in[29]; const float* db1 = (const float*)d_in[30];
  const float* dW2 = (const float*)d_in[31]; const float* db2 = (const float*)d_in[32];
  float* out = (float*)d_out;
  (void)in_sizes; (void)n_in; (void)out_size;

  char* ws = (char*)d_ws; size_t off = 0;
  auto alloc = [&](size_t bytes) -> void* {
    void* p = ws + off; off += (bytes + 255) & ~(size_t)255; return p;
  };
  ushort* WtT  = (ushort*)alloc((size_t)1024 * 1024 * 2);
  ushort* WgT  = (ushort*)alloc((size_t)1024 * 896 * 2);
  ushort* WcT  = (ushort*)alloc((size_t)1024 * 128 * 2);
  ushort* E0T  = (ushort*)alloc((size_t)1024 * 1024 * 2);
  ushort* E1T  = (ushort*)alloc((size_t)512 * 1024 * 2);
  ushort* E2T  = (ushort*)alloc((size_t)256 * 512 * 2);
  ushort* D0T  = (ushort*)alloc((size_t)512 * 256 * 2);
  ushort* D1T  = (ushort*)alloc((size_t)1024 * 512 * 2);
  ushort* D2T  = (ushort*)alloc((size_t)1024 * 1024 * 2);
  ushort* embB = (ushort*)alloc((size_t)128 * 1024 * 2);
  ushort* teraw= (ushort*)alloc((size_t)128 * 1024 * 2);
  ushort* tetab= (ushort*)alloc((size_t)128 * 1024 * 2);
  const size_t woff = off;

  // merged layout (preferred)
  ushort* G  = (ushort*)alloc((size_t)2 * B * 896 * 2);
  ushort* Cc = (ushort*)alloc((size_t)2 * B * 128 * 2);
  ushort* Z  = (ushort*)alloc((size_t)2 * S * 256 * 2);
  ushort* Xs = (ushort*)alloc((size_t)2 * S * 1024 * 2);
  ushort* b0 = (ushort*)alloc((size_t)2 * S * 1024 * 2);
  ushort* b1 = (ushort*)alloc((size_t)2 * S * 1024 * 2);
  const bool merged = (off <= ws_size);

  // fallback layout (per-branch)
  ushort *fG[2], *fC[2], *fZ[2], *fX[2], *fb0, *fb1, *fxh;
  if (!merged) {
    off = woff;
    fG[0] = (ushort*)alloc((size_t)B * 896 * 2);
    fG[1] = (ushort*)alloc((size_t)B * 896 * 2);
    fC[0] = (ushort*)alloc((size_t)B * 128 * 2);
    fC[1] = (ushort*)alloc((size_t)B * 128 * 2);
    fZ[0] = (ushort*)alloc((size_t)S * 256 * 2);
    fZ[1] = (ushort*)alloc((size_t)S * 256 * 2);
    fX[0] = (ushort*)alloc((size_t)S * 1024 * 2);
    fX[1] = (ushort*)alloc((size_t)S * 1024 * 2);
    fb0   = (ushort*)alloc((size_t)S * 1024 * 2);
    fb1   = (ushort*)alloc((size_t)S * 1024 * 2);
    fxh   = (ushort*)alloc((size_t)S * 1024 * 2);
  }

  // --- merged weight transpose (9 -> 1 dispatch) ---
  TP9 tp;
  tp.t[0] = {Wt,  WtT, 1024, 1024, 1024};
  tp.t[1] = {Wg,  WgT,  772, 1024,  896};
  tp.t[2] = {Wc,  WcT,  100, 1024,  128};
  tp.t[3] = {eW0, E0T, 1024, 1024, 1024};
  tp.t[4] = {eW1, E1T, 1024,  512, 1024};
  tp.t[5] = {eW2, E2T,  512,  256,  512};
  tp.t[6] = {dW0, D0T,  256,  512,  256};
  tp.t[7] = {dW1, D1T,  512, 1024,  512};
  tp.t[8] = {dW2, D2T, 1024, 1024, 1024};
  trans_all<<<dim3(32, 32, 9), dim3(32, 8), 0, stream>>>(tp);

  // --- merged conv_pad (5 -> 1 dispatch) ---
  {
    CP5 cp;
    const float* srcs[5] = {embed, g1, g2, c1, c2};
    ushort* dsts[5];
    int cins[5]  = {1024, 772, 772, 100, 100};
    int cpads[5] = {1024, 896, 896, 128, 128};
    int rs[5]    = {128, B, B, B, B};
    if (merged) {
      dsts[0] = embB; dsts[1] = G; dsts[2] = G + (size_t)B * 896;
      dsts[3] = Cc;   dsts[4] = Cc + (size_t)B * 128;
    } else {
      dsts[0] = embB; dsts[1] = fG[0]; dsts[2] = fG[1];
      dsts[3] = fC[0]; dsts[4] = fC[1];
    }
    size_t cum = 0;
    for (int i = 0; i < 5; ++i) {
      cp.s[i] = {srcs[i], dsts[i], cins[i], cpads[i],
                 (size_t)rs[i] * cpads[i]};
      cum += cp.s[i].total; cp.cum[i] = cum;
    }
    const int grid = 2048;
    conv_all<<<grid, 256, 0, stream>>>(cp, cum);
  }

  gemm128<0><<<dim3(8, 1), 256, 0, stream>>>(embB, WtT, bt, teraw, 128, 1024, 1024);
  ln_te<<<128, 256, 0, stream>>>(teraw, lntg, lntb, tetab);

  const size_t ZLEN = (size_t)S * 256;
  const int n8x = S * 1024 / 8;

  // pipeline over nS samples; E1/E2 commuted (GEMM raw -> mixact on d_out).
  auto pipeline = [&](ushort* Gp, ushort* Cp, const int* ta, const int* tb,
                      const float* Aa, const float* Ab2, int split, int nS,
                      ushort* Xp, ushort* p0, ushort* p1, ushort* Zp, ushort* xh) {
    const int Ms = nS * 3;
    gemm256<0><<<dim3(4, nS / 256), 512, 0, stream>>>(Gp, WgT, bg, p0, nS, 1024, 896);
    gemm128<0><<<dim3(8, nS / 128), 256, 0, stream>>>(Cp, WcT, bc, p1, nS, 1024, 128);
    assembleX<<<nS, 256, 0, stream>>>(ta, tb, split, tetab, p0, p1,
                                      lngg, lngb, lncg, lncb, Xp);
    // E0 (mix-before; d_in == d_out)
    mix3<<<(nS << 7) / 256, 256, 0, stream>>>(Xp, Aa, Ab2, split, p0, 1024, 7, nS);
    gemm256<0><<<dim3(4, Ms / 256), 512, 0, stream>>>(p0, E0T, eb0, p1, Ms, 1024, 1024);
    // E1 commuted: raw GEMM 1024->512, then relu(A*y + b) on d=512
    gemm256<2><<<dim3(2, Ms / 256), 512, 0, stream>>>(p1, E1T, nullptr, p0, Ms, 512, 1024);
    mixact<<<(nS << 6) / 256, 256, 0, stream>>>(p0, Aa, Ab2, split, eb1, p1, 512, 6, nS);
    // E2 commuted: raw GEMM 512->256, then relu(A*y + b) on d=256 -> Z
    gemm128<2><<<dim3(2, Ms / 128), 256, 0, stream>>>(p1, E2T, nullptr, p0, Ms, 256, 512);
    mixact<<<(nS << 5) / 256, 256, 0, stream>>>(p0, Aa, Ab2, split, eb2, Zp, 256, 5, nS);
    // decoder (expanding; mix-before)
    mix3<<<(nS << 5) / 256, 256, 0, stream>>>(Zp, Aa, Ab2, split, p0, 256, 5, nS);
    gemm128<1><<<dim3(4, Ms / 128), 256, 0, stream>>>(p0, D0T, db0, p1, Ms, 512, 256);
    mix3<<<(nS << 6) / 256, 256, 0, stream>>>(p1, Aa, Ab2, split, p0, 512, 6, nS);
    gemm256<1><<<dim3(4, Ms / 256), 512, 0, stream>>>(p0, D1T, db1, p1, Ms, 1024, 512);
    mix3<<<(nS << 7) / 256, 256, 0, stream>>>(p1, Aa, Ab2, split, p0, 1024, 7, nS);
    gemm256<1><<<dim3(4, Ms / 256), 512, 0, stream>>>(p0, D2T, db2, xh, Ms, 1024, 1024);
  };

  if (merged) {
    pipeline(G, Cc, t1, t2, A1, A2, B, 2 * B, Xs, b0, b1, Z, b1);
    xloss2_k<<<n8x / 256, 256, 0, stream>>>(
        Xs, b1, Xs + (size_t)S * 1024, b1 + (size_t)S * 1024, out + ZLEN, n8x);
    zloss_k<<<(int)(ZLEN / 8 / 256), 256, 0, stream>>>(Z, Z + ZLEN, out, (int)(ZLEN / 8));
  } else {
    for (int br = 0; br < 2; ++br) {
      const int*   t    = br ? t2 : t1;
      const float* Aadj = br ? A2 : A1;
      pipeline(fG[br], fC[br], t, t, Aadj, Aadj, B, B,
               fX[br], fb0, fb1, fZ[br], br ? fb1 : fxh);
    }
    xloss2_k<<<n8x / 256, 256, 0, stream>>>(fX[0], fxh, fX[1], fb1, out + ZLEN, n8x);
    zloss_k<<<(int)(ZLEN / 8 / 256), 256, 0, stream>>>(fZ[0], fZ[1], out, (int)(ZLEN / 8));
  }
}